// Round 9
// baseline (8208.302 us; speedup 1.0000x reference)
//
#include <hip/hip_runtime.h>
#include <hip/hip_bf16.h>

typedef float f32x4  __attribute__((ext_vector_type(4)));
typedef float f32x16 __attribute__((ext_vector_type(16)));
typedef short short8v __attribute__((ext_vector_type(8)));
typedef unsigned int uint;

constexpr int TSTEPS = 512;
constexpr int NSTAGE = TSTEPS * 4;     // 2048 RK substages

union FragU { uint u[4]; short8v v; };

__device__ __forceinline__ float silu_f(float x) {
    return __fdividef(x, 1.0f + __expf(-x));
}

// ---- setup-path split (RNE, bf16 pattern in top 16 bits) ----
__device__ __forceinline__ uint bf16_rne(float x) {
    uint ux = __float_as_uint(x);
    return (ux + 0x7FFFu + ((ux >> 16) & 1u)) & 0xFFFF0000u;
}
__device__ __forceinline__ void split2u(float x, uint &h, uint &l) {
    h = bf16_rne(x);
    float rem = x - __uint_as_float(h);
    l = bf16_rne(rem);
}

// ---- hot-path split via v_cvt_pk_bf16_f32 (bit-identical to split2u) ----
__device__ __forceinline__ uint cvtpk(float a, float b) {
    union { __hip_bfloat162 h; uint u; } cv;
    cv.h = __float22bfloat162_rn(make_float2(a, b));
    return cv.u;
}
__device__ __forceinline__ void split4_pk(const f32x4 v, uint2 &hi, uint2 &lo) {
    hi.x = cvtpk(v.x, v.y);
    hi.y = cvtpk(v.z, v.w);
    float h0 = __uint_as_float(hi.x << 16);
    float h1 = __uint_as_float(hi.x & 0xFFFF0000u);
    float h2 = __uint_as_float(hi.y << 16);
    float h3 = __uint_as_float(hi.y & 0xFFFF0000u);
    lo.x = cvtpk(v.x - h0, v.y - h1);
    lo.y = cvtpk(v.z - h2, v.w - h3);
}

// x1 LDS layout: [lev][kt(8)][gk(2)][b(32)][e(8 shorts)]
#define SX1(lev,kt,gk,b) (((((lev)*8+(kt))*2+(gk))*32+(b))*8)

// 512 threads / 8 waves / 64 rows per block (grid 256 = 1 block/CU exactly).
// Waves 0-3 = group A (rows 0-31), waves 4-7 = group B (rows 32-63), group B
// runs ONE HALF-STAGE behind: every inter-barrier region pairs one group's
// P1 (split/L1-MFMA/silu/x1-write: VALU-heavy) with the other group's
// P2 (L2 32xMFMA + L3 dot: MFMA-heavy) -> cross-wave MFMA||VALU overlap on
// each SIMD, and barriers per group-stage drop from 2 to 1.
// MFMA: 32x32x16 bf16, 2-term RNE split (4 products, exact), as v8.
__global__ __launch_bounds__(512, 1)
void odernn_v9(const float* __restrict__ quat,
               const float* __restrict__ W1, const float* __restrict__ b1,
               const float* __restrict__ W2, const float* __restrict__ b2,
               const float* __restrict__ W3, const float* __restrict__ b3,
               float* __restrict__ out)
{
    __shared__ short sx1[2][2 * 8 * 2 * 32 * 8];   // per-group x1, 16 KB each
    __shared__ float sb1[128];
    __shared__ float sb2[128];
    __shared__ float sW3[512];
    __shared__ float sk3[2][4][32][4];             // per-group L3 partials

    const int tid  = threadIdx.x;
    const int wave = tid >> 6;
    const int role = wave >> 2;     // 0 = group A, 1 = group B
    const int w    = wave & 3;      // j-slice within the group
    const int lane = tid & 63;
    const int b    = lane & 31;     // batch col
    const int gp   = lane >> 5;     // k/lane group
    const int rowbase = blockIdx.x * 64 + role * 32;

    if (tid < 128) { sb1[tid] = b1[tid]; sb2[tid] = b2[tid]; }
    if (tid < 512) sW3[tid] = W3[tid];

    // ---- persistent weight fragments (per wave, j = 32w + b) ----
    short8v A2[8][2];
#pragma unroll
    for (int kt = 0; kt < 8; ++kt) {
#pragma unroll
        for (int e = 0; e < 8; ++e) {
            float x = W2[(16 * kt + 8 * gp + e) * 128 + (32 * w + b)];
            uint h2_, l2_; split2u(x, h2_, l2_);
            A2[kt][0][e] = (short)(h2_ >> 16);
            A2[kt][1][e] = (short)(l2_ >> 16);
        }
    }
    short8v A1;
#pragma unroll
    for (int e = 0; e < 8; ++e) {
        float x = W1[e * 128 + (32 * w + b)];
        uint h1_, l1_; split2u(x, h1_, l1_);
        A1[e] = (short)((gp ? l1_ : h1_) >> 16);
    }
    f32x4 b3v = *(const f32x4*)b3;

    __syncthreads();

    const f32x4 Z4 = {0.0f, 0.0f, 0.0f, 0.0f};
    f32x4 h  = {1.0f, 0.0f, 0.0f, 0.0f};
    f32x4 hnew = Z4, k1 = Z4, k2 = Z4, k3v = Z4, q = Z4;
    uint2 qhi = {0, 0}, qlo = {0, 0};
    const float* qp = quat + (size_t)(rowbase + b) * TSTEPS * 4;
    short* const sx1g = &sx1[role][0];

    // ---- P1(s): finish stage s-1 (ks reduce + state update), then stage-s
    //      input build + layer1 + silu + split + x1 write ----
    auto P1 = [&](int s) {
        if (s > 0) {
            const int sp = (s - 1) & 3;
            f32x4 ks = b3v;
#pragma unroll
            for (int w2 = 0; w2 < 4; ++w2)
                ks += *(const f32x4*)&sk3[role][w2][b][0];
            const float wgt = (sp == 1 || sp == 2) ? 0.375f : 0.125f;
            hnew += ks * wgt;
            if (sp == 0)      k1  = ks;
            else if (sp == 1) k2  = ks;
            else if (sp == 2) k3v = ks;
            else { h += hnew; hnew = Z4; }
        }
        if (s >= NSTAGE) return;           // final call: update only
        const int sub = s & 3;
        if (sub == 0) {
            q = *(const f32x4*)(qp + (size_t)(s >> 2) * 4);
            split4_pk(q, qhi, qlo);
        }
        f32x4 hs = h;
        if (sub == 1)      hs += k1 * (1.0f / 3.0f);
        else if (sub == 2) hs += k2 - k1 * (1.0f / 3.0f);
        else if (sub == 3) hs += k1 - k2 + k3v;

        uint2 hhi, hlo;
        split4_pk(hs, hhi, hlo);
        FragU b0a, b0b;
        b0a.u[0] = gp ? hlo.x : hhi.x;  b0a.u[1] = gp ? hlo.y : hhi.y;
        b0a.u[2] = gp ? qlo.x : qhi.x;  b0a.u[3] = gp ? qlo.y : qhi.y;
        b0b.u[0] = gp ? hhi.x : hlo.x;  b0b.u[1] = gp ? hhi.y : hlo.y;
        b0b.u[2] = gp ? qhi.x : qlo.x;  b0b.u[3] = gp ? qhi.y : qlo.y;

        f32x16 c1;
#pragma unroll
        for (int qd = 0; qd < 4; ++qd) {
            f32x4 bv = *(const f32x4*)&sb1[32 * w + 8 * qd + 4 * gp];
            c1[4*qd+0] = bv.x; c1[4*qd+1] = bv.y;
            c1[4*qd+2] = bv.z; c1[4*qd+3] = bv.w;
        }
        c1 = __builtin_amdgcn_mfma_f32_32x32x16_bf16(A1, b0a.v, c1, 0, 0, 0);
        c1 = __builtin_amdgcn_mfma_f32_32x32x16_bf16(A1, b0b.v, c1, 0, 0, 0);

#pragma unroll
        for (int qd = 0; qd < 4; ++qd) {
            f32x4 sv;
            sv.x = silu_f(c1[4*qd+0]); sv.y = silu_f(c1[4*qd+1]);
            sv.z = silu_f(c1[4*qd+2]); sv.w = silu_f(c1[4*qd+3]);
            uint2 phi, plo;
            split4_pk(sv, phi, plo);
            const int kt = 2 * w + (qd >> 1);
            const int gk = qd & 1;
            *(uint2*)&sx1g[SX1(0, kt, gk, b) + 4 * gp] = phi;
            *(uint2*)&sx1g[SX1(1, kt, gk, b) + 4 * gp] = plo;
        }
    };

    // ---- P2(s): layer2 (full K, dual accumulator chains) + layer3 dot +
    //      per-wave partial write ----
    auto P2 = [&](int s) {
        (void)s;
        f32x16 u, vv;
#pragma unroll
        for (int qd = 0; qd < 4; ++qd) {
            f32x4 bv = *(const f32x4*)&sb2[32 * w + 8 * qd + 4 * gp];
            u[4*qd+0] = bv.x; u[4*qd+1] = bv.y;
            u[4*qd+2] = bv.z; u[4*qd+3] = bv.w;
        }
#pragma unroll
        for (int i = 0; i < 16; ++i) vv[i] = 0.0f;
#pragma unroll
        for (int kt = 0; kt < 8; ++kt) {
            short8v Bh = *(const short8v*)&sx1g[SX1(0, kt, gp, b)];
            short8v Bl = *(const short8v*)&sx1g[SX1(1, kt, gp, b)];
            if (kt & 1) {
                vv = __builtin_amdgcn_mfma_f32_32x32x16_bf16(A2[kt][1], Bl, vv, 0, 0, 0);
                vv = __builtin_amdgcn_mfma_f32_32x32x16_bf16(A2[kt][1], Bh, vv, 0, 0, 0);
                vv = __builtin_amdgcn_mfma_f32_32x32x16_bf16(A2[kt][0], Bl, vv, 0, 0, 0);
                vv = __builtin_amdgcn_mfma_f32_32x32x16_bf16(A2[kt][0], Bh, vv, 0, 0, 0);
            } else {
                u = __builtin_amdgcn_mfma_f32_32x32x16_bf16(A2[kt][1], Bl, u, 0, 0, 0);
                u = __builtin_amdgcn_mfma_f32_32x32x16_bf16(A2[kt][1], Bh, u, 0, 0, 0);
                u = __builtin_amdgcn_mfma_f32_32x32x16_bf16(A2[kt][0], Bl, u, 0, 0, 0);
                u = __builtin_amdgcn_mfma_f32_32x32x16_bf16(A2[kt][0], Bh, u, 0, 0, 0);
            }
        }

        f32x4 p = {0.0f, 0.0f, 0.0f, 0.0f};
#pragma unroll
        for (int i = 0; i < 16; ++i) {
            const int j = 32 * w + 8 * (i >> 2) + (i & 3) + 4 * gp;
            const float xv = silu_f(u[i] + vv[i]);
            p += xv * (*(const f32x4*)&sW3[j * 4]);
        }
        p.x += __shfl_xor(p.x, 32, 64);
        p.y += __shfl_xor(p.y, 32, 64);
        p.z += __shfl_xor(p.z, 32, 64);
        p.w += __shfl_xor(p.w, 32, 64);
        if (lane < 32) *(f32x4*)&sk3[role][w][lane][0] = p;
    };

    // ---- staggered half-iteration pipeline: role-B is one half-step behind.
    // Every wave executes exactly one barrier per half-iteration (uniform). ----
    for (int hi = 0; hi < 2 * NSTAGE + 2; ++hi) {
        const int myhi = hi - role;
        if (myhi >= 0 && myhi <= 2 * NSTAGE) {
            if ((myhi & 1) == 0) P1(myhi >> 1);
            else                 P2(myhi >> 1);
        }
        __syncthreads();
    }

    if (w == 0 && lane < 32)
        *(f32x4*)&out[(size_t)(rowbase + lane) * 4] = h;
}

extern "C" void kernel_launch(void* const* d_in, const int* in_sizes, int n_in,
                              void* d_out, int out_size, void* d_ws, size_t ws_size,
                              hipStream_t stream)
{
    const float* quat = (const float*)d_in[0];
    const float* W1   = (const float*)d_in[1];
    const float* b1   = (const float*)d_in[2];
    const float* W2   = (const float*)d_in[3];
    const float* b2   = (const float*)d_in[4];
    const float* W3   = (const float*)d_in[5];
    const float* b3   = (const float*)d_in[6];
    float* out        = (float*)d_out;

    const int B = in_sizes[0] / (TSTEPS * 4);   // 16384
    dim3 grid(B / 64), block(512);
    hipLaunchKernelGGL(odernn_v9, grid, block, 0, stream,
                       quat, W1, b1, W2, b2, W3, b3, out);
}

// Round 10
// 6752.592 us; speedup vs baseline: 1.2156x; 1.2156x over previous
//
#include <hip/hip_runtime.h>
#include <hip/hip_bf16.h>

typedef float f32x4  __attribute__((ext_vector_type(4)));
typedef float f32x16 __attribute__((ext_vector_type(16)));
typedef short short8v __attribute__((ext_vector_type(8)));
typedef unsigned int uint;

constexpr int TSTEPS = 512;

union FragU { uint u[4]; short8v v; };

__device__ __forceinline__ float silu_f(float x) {
    return __fdividef(x, 1.0f + __expf(-x));
}

// ---- setup-path split (RNE, bf16 pattern in top 16 bits) ----
__device__ __forceinline__ uint bf16_rne(float x) {
    uint ux = __float_as_uint(x);
    return (ux + 0x7FFFu + ((ux >> 16) & 1u)) & 0xFFFF0000u;
}
__device__ __forceinline__ void split2u(float x, uint &h, uint &l) {
    h = bf16_rne(x);
    float rem = x - __uint_as_float(h);
    l = bf16_rne(rem);
}

// ---- hot-path split via v_cvt_pk_bf16_f32 (bit-identical to split2u) ----
__device__ __forceinline__ uint cvtpk(float a, float b) {
    union { __hip_bfloat162 h; uint u; } cv;
    cv.h = __float22bfloat162_rn(make_float2(a, b));
    return cv.u;
}
__device__ __forceinline__ void split4_pk(const f32x4 v, uint2 &hi, uint2 &lo) {
    hi.x = cvtpk(v.x, v.y);
    hi.y = cvtpk(v.z, v.w);
    float h0 = __uint_as_float(hi.x << 16);
    float h1 = __uint_as_float(hi.x & 0xFFFF0000u);
    float h2 = __uint_as_float(hi.y << 16);
    float h3 = __uint_as_float(hi.y & 0xFFFF0000u);
    lo.x = cvtpk(v.x - h0, v.y - h1);
    lo.y = cvtpk(v.z - h2, v.w - h3);
}

// x1 LDS layout: [lev][kt(8)][gk(2)][b(32)][e(8 shorts)]
#define SX1(lev,kt,gk,b) (((((lev)*8+(kt))*2+(gk))*32+(b))*8)

// 256 threads / 4 waves / 32 batch rows per block; grid 512 = 2 blocks/CU,
// all rows resident. 32x32x16 MFMA, 2-term RNE split.
// v10 changes vs v8 (LDS-pipe relief): W3 slice held in 64 VGPRs (-16
// ds_read_b128/stage), L2 uses 3-product split MFMA (drop Wlo*Xlo, 32->24
// MFMAs, shorter chains), q double-buffered across t (hides HBM latency
// from the barrier vmcnt drain).
__global__ __launch_bounds__(256, 2)
void odernn_v10(const float* __restrict__ quat,
                const float* __restrict__ W1, const float* __restrict__ b1,
                const float* __restrict__ W2, const float* __restrict__ b2,
                const float* __restrict__ W3, const float* __restrict__ b3,
                float* __restrict__ out)
{
    __shared__ short sx1[2 * 8 * 2 * 32 * 8];   // 16 KB
    __shared__ float sb1[128];
    __shared__ float sb2[128];
    __shared__ float sk3[4][32][4];             // 2 KB

    const int tid  = threadIdx.x;
    const int w    = tid >> 6;
    const int lane = tid & 63;
    const int b    = lane & 31;    // batch col
    const int gp   = lane >> 5;    // k/lane group
    const int rowbase = blockIdx.x * 32;

    if (tid < 128) { sb1[tid] = b1[tid]; sb2[tid] = b2[tid]; }

    // ---- persistent weight fragments ----
    short8v A2[8][2];   // W2^T: A2[kt][lev][e] = lev(W2[k=16kt+8gp+e][j=32w+b])
#pragma unroll
    for (int kt = 0; kt < 8; ++kt) {
#pragma unroll
        for (int e = 0; e < 8; ++e) {
            float x = W2[(16 * kt + 8 * gp + e) * 128 + (32 * w + b)];
            uint h2_, l2_; split2u(x, h2_, l2_);
            A2[kt][0][e] = (short)(h2_ >> 16);
            A2[kt][1][e] = (short)(l2_ >> 16);
        }
    }
    short8v A1;         // W1^T packed: group0 lanes Wh, group1 lanes Wl
#pragma unroll
    for (int e = 0; e < 8; ++e) {
        float x = W1[e * 128 + (32 * w + b)];
        uint h1_, l1_; split2u(x, h1_, l1_);
        A1[e] = (short)((gp ? l1_ : h1_) >> 16);
    }
    // per-lane j-slice of W3 in registers: i -> j = 32w + 8*(i>>2) + (i&3) + 4gp
    f32x4 W3r[16];
#pragma unroll
    for (int i = 0; i < 16; ++i) {
        const int j = 32 * w + 8 * (i >> 2) + (i & 3) + 4 * gp;
        W3r[i] = *(const f32x4*)&W3[j * 4];
    }
    f32x4 b3v = *(const f32x4*)b3;

    __syncthreads();

    f32x4 h  = {1.0f, 0, 0, 0};
    f32x4 k1 = {0,0,0,0}, k2 = {0,0,0,0}, k3v = {0,0,0,0};
    const float* qp = quat + (size_t)(rowbase + b) * TSTEPS * 4;

    f32x4 qnext = *(const f32x4*)qp;    // double-buffered q

#pragma unroll 1
    for (int t = 0; t < TSTEPS; ++t) {
        const f32x4 q = qnext;
        const int tn = (t + 1 < TSTEPS) ? t + 1 : t;
        qnext = *(const f32x4*)(qp + 4 * tn);   // prefetch next t

        uint2 qhi, qlo;
        split4_pk(q, qhi, qlo);
        f32x4 hnew = {0,0,0,0};

#pragma unroll
        for (int s = 0; s < 4; ++s) {
            f32x4 hs = h;
            if (s == 1)      hs += k1 * (1.0f/3.0f);
            else if (s == 2) hs += k2 - k1 * (1.0f/3.0f);
            else if (s == 3) hs += k1 - k2 + k3v;

            // ---- B0 pair: own-level and swapped-level ----
            uint2 hhi, hlo;
            split4_pk(hs, hhi, hlo);
            FragU b0a, b0b;
            b0a.u[0] = gp ? hlo.x : hhi.x;  b0a.u[1] = gp ? hlo.y : hhi.y;
            b0a.u[2] = gp ? qlo.x : qhi.x;  b0a.u[3] = gp ? qlo.y : qhi.y;
            b0b.u[0] = gp ? hhi.x : hlo.x;  b0b.u[1] = gp ? hhi.y : hlo.y;
            b0b.u[2] = gp ? qhi.x : qlo.x;  b0b.u[3] = gp ? qhi.y : qlo.y;

            // ---- layer 1: 2 MFMAs give all 4 level products ----
            f32x16 c1;
#pragma unroll
            for (int qd = 0; qd < 4; ++qd) {
                f32x4 bv = *(const f32x4*)&sb1[32 * w + 8 * qd + 4 * gp];
                c1[4*qd+0] = bv.x; c1[4*qd+1] = bv.y;
                c1[4*qd+2] = bv.z; c1[4*qd+3] = bv.w;
            }
            c1 = __builtin_amdgcn_mfma_f32_32x32x16_bf16(A1, b0a.v, c1, 0, 0, 0);
            c1 = __builtin_amdgcn_mfma_f32_32x32x16_bf16(A1, b0b.v, c1, 0, 0, 0);

            // ---- silu + producer split -> LDS ----
#pragma unroll
            for (int qd = 0; qd < 4; ++qd) {
                f32x4 sv;
                sv.x = silu_f(c1[4*qd+0]); sv.y = silu_f(c1[4*qd+1]);
                sv.z = silu_f(c1[4*qd+2]); sv.w = silu_f(c1[4*qd+3]);
                uint2 phi, plo;
                split4_pk(sv, phi, plo);
                const int kt = 2 * w + (qd >> 1);
                const int gk = qd & 1;
                *(uint2*)&sx1[SX1(0, kt, gk, b) + 4 * gp] = phi;
                *(uint2*)&sx1[SX1(1, kt, gk, b) + 4 * gp] = plo;
            }
            __syncthreads();

            // ---- layer 2: full K=128, 3-product split MFMA per ktile ----
            f32x16 u, vv;
#pragma unroll
            for (int qd = 0; qd < 4; ++qd) {
                f32x4 bv = *(const f32x4*)&sb2[32 * w + 8 * qd + 4 * gp];
                u[4*qd+0] = bv.x; u[4*qd+1] = bv.y;
                u[4*qd+2] = bv.z; u[4*qd+3] = bv.w;
            }
#pragma unroll
            for (int i = 0; i < 16; ++i) vv[i] = 0.0f;
#pragma unroll
            for (int kt = 0; kt < 8; ++kt) {
                short8v Bh = *(const short8v*)&sx1[SX1(0, kt, gp, b)];
                short8v Bl = *(const short8v*)&sx1[SX1(1, kt, gp, b)];
                if (kt & 1) {
                    vv = __builtin_amdgcn_mfma_f32_32x32x16_bf16(A2[kt][1], Bh, vv, 0, 0, 0);
                    vv = __builtin_amdgcn_mfma_f32_32x32x16_bf16(A2[kt][0], Bl, vv, 0, 0, 0);
                    vv = __builtin_amdgcn_mfma_f32_32x32x16_bf16(A2[kt][0], Bh, vv, 0, 0, 0);
                } else {
                    u = __builtin_amdgcn_mfma_f32_32x32x16_bf16(A2[kt][1], Bh, u, 0, 0, 0);
                    u = __builtin_amdgcn_mfma_f32_32x32x16_bf16(A2[kt][0], Bl, u, 0, 0, 0);
                    u = __builtin_amdgcn_mfma_f32_32x32x16_bf16(A2[kt][0], Bh, u, 0, 0, 0);
                }
            }

            // ---- layer 3: fp32 dot with register-resident W3 rows ----
            f32x4 p = {0.0f, 0.0f, 0.0f, 0.0f};
#pragma unroll
            for (int i = 0; i < 16; ++i) {
                const float xv = silu_f(u[i] + vv[i]);
                p += xv * W3r[i];
            }
            p.x += __shfl_xor(p.x, 32, 64);
            p.y += __shfl_xor(p.y, 32, 64);
            p.z += __shfl_xor(p.z, 32, 64);
            p.w += __shfl_xor(p.w, 32, 64);
            if (lane < 32) *(f32x4*)&sk3[w][lane][0] = p;
            __syncthreads();

            f32x4 ks = b3v;
#pragma unroll
            for (int w2 = 0; w2 < 4; ++w2)
                ks += *(const f32x4*)&sk3[w2][b][0];

            const float wgt = (s == 1 || s == 2) ? 0.375f : 0.125f;
            hnew += ks * wgt;
            if (s == 0)      k1  = ks;
            else if (s == 1) k2  = ks;
            else if (s == 2) k3v = ks;
        }
        h += hnew;
    }

    if (tid < 32)
        *(f32x4*)&out[(size_t)(rowbase + tid) * 4] = h;
}

extern "C" void kernel_launch(void* const* d_in, const int* in_sizes, int n_in,
                              void* d_out, int out_size, void* d_ws, size_t ws_size,
                              hipStream_t stream)
{
    const float* quat = (const float*)d_in[0];
    const float* W1   = (const float*)d_in[1];
    const float* b1   = (const float*)d_in[2];
    const float* W2   = (const float*)d_in[3];
    const float* b2   = (const float*)d_in[4];
    const float* W3   = (const float*)d_in[5];
    const float* b3   = (const float*)d_in[6];
    float* out        = (float*)d_out;

    const int B = in_sizes[0] / (TSTEPS * 4);   // 16384
    dim3 grid(B / 32), block(256);
    hipLaunchKernelGGL(odernn_v10, grid, block, 0, stream,
                       quat, W1, b1, W2, b2, W3, b3, out);
}